// Round 1
// baseline (541.213 us; speedup 1.0000x reference)
//
#include <hip/hip_runtime.h>
#include <math.h>

#define BE   256
#define DIM  256
#define OUTD 128
#define LCL  256
#define LEV  512
#define NEGV -1e18f

// ---------------------------------------------------------------------------
// K1: per-pair means of claim/evidence, then bias = mean @ W[D:2D]
// grid: 256 blocks (one per (b,e)), 256 threads
// ---------------------------------------------------------------------------
__global__ __launch_bounds__(256) void k_bias(
    const float* __restrict__ claim, const float* __restrict__ evidence,
    const float* __restrict__ W1, const float* __restrict__ W2,
    float* __restrict__ bias_e, float* __restrict__ bias_c)
{
    const int pair = blockIdx.x;
    const int t = threadIdx.x;
    __shared__ float cm[DIM];
    __shared__ float em[DIM];
    const float* cp = claim + (size_t)pair * LCL * DIM;
    const float* ep = evidence + (size_t)pair * LEV * DIM;
    float s = 0.f;
    for (int l = 0; l < LCL; ++l) s += cp[l * DIM + t];
    cm[t] = s * (1.0f / LCL);
    s = 0.f;
    for (int l = 0; l < LEV; ++l) s += ep[l * DIM + t];
    em[t] = s * (1.0f / LEV);
    __syncthreads();
    if (t < OUTD) {
        // bias for evidence side: c_mean @ W1[D:]
        float b = 0.f;
        for (int d = 0; d < DIM; ++d) b += cm[d] * W1[(DIM + d) * OUTD + t];
        bias_e[pair * OUTD + t] = b;
    } else {
        // bias for claim side: e_mean @ W2[D:]
        const int o = t - OUTD;
        float b = 0.f;
        for (int d = 0; d < DIM; ++d) b += em[d] * W2[(DIM + d) * OUTD + o];
        bias_c[pair * OUTD + o] = b;
    }
}

// ---------------------------------------------------------------------------
// K2: att[l] = sum_o tanh(seq[l,:] @ W[:, o] + bias[o]) * w[o]
// grid: (BE, L/32) blocks, 256 threads.
// Thread map: og = t & 63 -> o pair (2*og, 2*og+1); rg = t >> 6 -> 8 rows.
// One wave == one rg, so the OUT-reduction is a 64-lane shuffle reduce.
// ---------------------------------------------------------------------------
template <int L>
__global__ __launch_bounds__(256) void k_att(
    const float* __restrict__ seq, const float* __restrict__ W,
    const float* __restrict__ wvec, const float* __restrict__ bias,
    float* __restrict__ att)
{
    constexpr int RT = 32;                 // rows per block tile
    const int pair = blockIdx.x;
    const int tile = blockIdx.y;
    const int t = threadIdx.x;
    __shared__ float stile[RT * DIM];      // 32 KB
    __shared__ float sb[OUTD];
    __shared__ float sw[OUTD];

    const float* sp = seq + ((size_t)pair * L + (size_t)tile * RT) * DIM;
    float4* st4 = (float4*)stile;
    const float4* sp4 = (const float4*)sp;
#pragma unroll
    for (int k = 0; k < (RT * DIM / 4) / 256; ++k)   // 8 float4 per thread
        st4[t + k * 256] = sp4[t + k * 256];
    if (t < OUTD) sb[t] = bias[pair * OUTD + t];
    else          sw[t - OUTD] = wvec[t - OUTD];
    __syncthreads();

    const int og = t & 63;
    const int rg = t >> 6;
    const int o0 = og * 2;

    float acc[8][2];
#pragma unroll
    for (int r = 0; r < 8; ++r) { acc[r][0] = 0.f; acc[r][1] = 0.f; }

    const float* srow = stile + (rg * 8) * DIM;
    for (int d = 0; d < DIM; d += 4) {
        const float2 wv0 = *(const float2*)&W[(d + 0) * OUTD + o0];
        const float2 wv1 = *(const float2*)&W[(d + 1) * OUTD + o0];
        const float2 wv2 = *(const float2*)&W[(d + 2) * OUTD + o0];
        const float2 wv3 = *(const float2*)&W[(d + 3) * OUTD + o0];
#pragma unroll
        for (int r = 0; r < 8; ++r) {
            const float4 sv = *(const float4*)&srow[r * DIM + d];
            acc[r][0] += sv.x * wv0.x + sv.y * wv1.x + sv.z * wv2.x + sv.w * wv3.x;
            acc[r][1] += sv.x * wv0.y + sv.y * wv1.y + sv.z * wv2.y + sv.w * wv3.y;
        }
    }

    const float b0 = sb[o0], b1 = sb[o0 + 1];
    const float w0 = sw[o0], w1 = sw[o0 + 1];
#pragma unroll
    for (int r = 0; r < 8; ++r) {
        float v = tanhf(acc[r][0] + b0) * w0 + tanhf(acc[r][1] + b1) * w1;
#pragma unroll
        for (int off = 32; off > 0; off >>= 1) v += __shfl_xor(v, off, 64);
        if (og == 0)
            att[(size_t)pair * L + tile * RT + rg * 8 + r] = v;
    }
}

// ---------------------------------------------------------------------------
// K3: masked softmax over L, then out[d] = sum_l p[l] * seq[l, d]
// grid: 256 blocks (one per pair), 256 threads (thread == dim d)
// ---------------------------------------------------------------------------
template <int L>
__global__ __launch_bounds__(256) void k_soft(
    const float* __restrict__ seq, const int* __restrict__ mask,
    const float* __restrict__ att, float* __restrict__ outp)
{
    const int pair = blockIdx.x;
    const int t = threadIdx.x;
    __shared__ float p[L];
    __shared__ float red[8];

    float lmax = -INFINITY;
#pragma unroll
    for (int k = 0; k < L / 256; ++k) {
        const int i = t + k * 256;
        float a = att[(size_t)pair * L + i];
        const int m = mask[pair * L + i];
        a = m ? a : NEGV;
        p[i] = a;
        lmax = fmaxf(lmax, a);
    }
#pragma unroll
    for (int off = 32; off > 0; off >>= 1) lmax = fmaxf(lmax, __shfl_xor(lmax, off, 64));
    if ((t & 63) == 0) red[t >> 6] = lmax;
    __syncthreads();
    const float gmax = fmaxf(fmaxf(red[0], red[1]), fmaxf(red[2], red[3]));

    float lsum = 0.f;
#pragma unroll
    for (int k = 0; k < L / 256; ++k) {
        const int i = t + k * 256;
        const float e = expf(p[i] - gmax);
        p[i] = e;
        lsum += e;
    }
#pragma unroll
    for (int off = 32; off > 0; off >>= 1) lsum += __shfl_xor(lsum, off, 64);
    if ((t & 63) == 0) red[4 + (t >> 6)] = lsum;
    __syncthreads();
    const float gsum = red[4] + red[5] + red[6] + red[7];
    const float inv = 1.0f / gsum;

    const float* sp = seq + (size_t)pair * L * DIM + t;
    float o = 0.f;
    for (int l = 0; l < L; ++l) o += p[l] * sp[(size_t)l * DIM];
    outp[pair * DIM + t] = o * inv;
}

// ---------------------------------------------------------------------------
extern "C" void kernel_launch(void* const* d_in, const int* in_sizes, int n_in,
                              void* d_out, int out_size, void* d_ws, size_t ws_size,
                              hipStream_t stream) {
    const float* claim    = (const float*)d_in[0];
    const int*   cmask    = (const int*)  d_in[1];
    const float* evidence = (const float*)d_in[2];
    const int*   emask    = (const int*)  d_in[3];
    const float* W1       = (const float*)d_in[4];
    const float* w2       = (const float*)d_in[5];
    const float* W2       = (const float*)d_in[6];
    const float* w1       = (const float*)d_in[7];
    float* out = (float*)d_out;

    float* ws = (float*)d_ws;
    float* bias_e = ws;                       // 256*128
    float* bias_c = bias_e + BE * OUTD;       // 256*128
    float* att_e  = bias_c + BE * OUTD;       // 256*512
    float* att_c  = att_e + BE * LEV;         // 256*256

    k_bias<<<BE, 256, 0, stream>>>(claim, evidence, W1, W2, bias_e, bias_c);
    k_att<LEV><<<dim3(BE, LEV / 32), 256, 0, stream>>>(evidence, W1, w2, bias_e, att_e);
    k_att<LCL><<<dim3(BE, LCL / 32), 256, 0, stream>>>(claim, W2, w1, bias_c, att_c);
    // output order: c_hat first, then e_hat
    k_soft<LEV><<<BE, 256, 0, stream>>>(evidence, emask, att_e, out + BE * DIM);
    k_soft<LCL><<<BE, 256, 0, stream>>>(claim, cmask, att_c, out);
}

// Round 2
// 359.065 us; speedup vs baseline: 1.5073x; 1.5073x over previous
//
#include <hip/hip_runtime.h>
#include <hip/hip_bf16.h>
#include <math.h>

#define BE   256
#define DIM  256
#define OUTD 128
#define LCL  256
#define LEV  512
#define NEGV -1e18f

typedef short  bf16x8  __attribute__((ext_vector_type(8)));
typedef float  floatx4 __attribute__((ext_vector_type(4)));

union BF1 { __hip_bfloat16 h; unsigned short u; };
union BF2 { __hip_bfloat162 h; unsigned int u; };

__device__ __forceinline__ float fast_tanh(float x) {
    float xc = fminf(fmaxf(x, -15.f), 15.f);
    float e = __expf(2.f * xc);                       // e^{2x}
    return (e - 1.f) * __builtin_amdgcn_rcpf(e + 1.f);
}

// ---------------------------------------------------------------------------
// K0: zero the mean accumulators (ws is poisoned 0xAA before every call)
// ---------------------------------------------------------------------------
__global__ __launch_bounds__(256) void k_zero(float* __restrict__ a) {
    a[blockIdx.x * 256 + threadIdx.x] = 0.f;
}

// ---------------------------------------------------------------------------
// K1: partial sums for claim/evidence means. grid (BE, 24): y<8 -> claim
// chunk (32 rows), y>=8 -> evidence chunk (32 rows). atomicAdd partials.
// ---------------------------------------------------------------------------
__global__ __launch_bounds__(256) void k_pmean(
    const float* __restrict__ claim, const float* __restrict__ evidence,
    float* __restrict__ cmean, float* __restrict__ emean)
{
    const int pair = blockIdx.x;
    const int ch = blockIdx.y;
    const int t = threadIdx.x;
    const float* src;
    float* dst;
    if (ch < 8) { src = claim + ((size_t)pair * LCL + ch * 32) * DIM; dst = cmean + pair * DIM; }
    else        { src = evidence + ((size_t)pair * LEV + (ch - 8) * 32) * DIM; dst = emean + pair * DIM; }
    float s = 0.f;
#pragma unroll
    for (int r = 0; r < 32; ++r) s += src[r * DIM + t];
    unsafeAtomicAdd(&dst[t], s);
}

// ---------------------------------------------------------------------------
// K2: bias_e = (cmean/LCL) @ W1[D:],  bias_c = (emean/LEV) @ W2[D:]
// ---------------------------------------------------------------------------
__global__ __launch_bounds__(256) void k_biasgemm(
    const float* __restrict__ cmean, const float* __restrict__ emean,
    const float* __restrict__ W1, const float* __restrict__ W2,
    float* __restrict__ bias_e, float* __restrict__ bias_c)
{
    const int pair = blockIdx.x;
    const int t = threadIdx.x;
    __shared__ float smc[DIM], sme[DIM];
    smc[t] = cmean[pair * DIM + t] * (1.f / LCL);
    sme[t] = emean[pair * DIM + t] * (1.f / LEV);
    __syncthreads();
    if (t < OUTD) {
        float b = 0.f;
        for (int d = 0; d < DIM; ++d) b += smc[d] * W1[(DIM + d) * OUTD + t];
        bias_e[pair * OUTD + t] = b;
    } else {
        const int o = t - OUTD;
        float b = 0.f;
        for (int d = 0; d < DIM; ++d) b += sme[d] * W2[(DIM + d) * OUTD + o];
        bias_c[pair * OUTD + o] = b;
    }
}

// ---------------------------------------------------------------------------
// K3: convert+transpose W[:D] (256x128 fp32) -> W^T (128x256 bf16)
// grid (128, 2), 256 threads
// ---------------------------------------------------------------------------
__global__ __launch_bounds__(256) void k_prepW(
    const float* __restrict__ W1, const float* __restrict__ W2,
    unsigned short* __restrict__ WT1, unsigned short* __restrict__ WT2)
{
    const int n = blockIdx.x;
    const float* W = blockIdx.y ? W2 : W1;
    unsigned short* WT = blockIdx.y ? WT2 : WT1;
    const int k = threadIdx.x;
    BF1 c; c.h = __float2bfloat16(W[(size_t)k * OUTD + n]);
    WT[n * DIM + k] = c.u;
}

// ---------------------------------------------------------------------------
// K4: MFMA attention-score kernel.
// att[l] = sum_o tanh( (seq @ W[:D])[l,o] + bias[o] ) * w[o]
// Block: 256 thr = 4 waves, tile 128 rows x 128 cols of the hidden h.
// Wave wv: wrow=wv>>1 (64-row half), wcolg=wv&1 (64-col half).
// Wave tile 64x64 via 4x4 grid of 16x16x32 MFMAs, K=256 in 2 LDS chunks.
// A staged fp32->bf16 in LDS (padded); B-frags streamed from global W^T (L2).
// ---------------------------------------------------------------------------
template <int L>
__global__ __launch_bounds__(256) void k_att(
    const float* __restrict__ seq, const unsigned short* __restrict__ WT,
    const float* __restrict__ wvec, const float* __restrict__ bias,
    float* __restrict__ att)
{
    constexpr int SAPC = 136;                 // padded k-stride (128+8) in bf16
    __shared__ unsigned short sA[128 * SAPC]; // 34816 B
    __shared__ float sred[128][2];

    const int pair = blockIdx.x;
    const int rowbase = blockIdx.y * 128;
    const int t = threadIdx.x;
    const int lane = t & 63;
    const int wv = t >> 6;
    const int wrow = wv >> 1, wcolg = wv & 1;
    const int q = lane >> 4, c16 = lane & 15;

    const float4* sp4 = (const float4*)(seq + ((size_t)pair * L + rowbase) * DIM);

    floatx4 acc[4][4];
#pragma unroll
    for (int ra = 0; ra < 4; ++ra)
#pragma unroll
        for (int ct = 0; ct < 4; ++ct) acc[ra][ct] = (floatx4){0.f, 0.f, 0.f, 0.f};

    const unsigned short* wbase = WT + (size_t)(wcolg * 64 + c16) * DIM + q * 8;
    bf16x8 bcur[4], bnxt[4];
#pragma unroll
    for (int ct = 0; ct < 4; ++ct)
        bcur[ct] = *(const bf16x8*)(wbase + ct * 16 * DIM);

    for (int kc = 0; kc < 2; ++kc) {
        __syncthreads();   // protect sA reuse across chunks
        // stage 128 rows x 128 k (fp32 -> bf16): 4096 float4 / 256 thr
#pragma unroll
        for (int i = 0; i < 16; ++i) {
            const int idx = t + i * 256;
            const int row = idx >> 5;
            const int f4 = idx & 31;
            const float4 v = sp4[row * 64 + kc * 32 + f4];
            BF2 lo, hi;
            lo.h = __float22bfloat162_rn(make_float2(v.x, v.y));
            hi.h = __float22bfloat162_rn(make_float2(v.z, v.w));
            *(uint2*)&sA[row * SAPC + f4 * 4] = make_uint2(lo.u, hi.u);
        }
        __syncthreads();
#pragma unroll
        for (int ks4 = 0; ks4 < 4; ++ks4) {
            const int ks = kc * 4 + ks4;
            if (ks < 7) {
#pragma unroll
                for (int ct = 0; ct < 4; ++ct)
                    bnxt[ct] = *(const bf16x8*)(wbase + ct * 16 * DIM + (ks + 1) * 32);
            }
            bf16x8 af[4];
#pragma unroll
            for (int ra = 0; ra < 4; ++ra)
                af[ra] = *(const bf16x8*)&sA[(wrow * 64 + ra * 16 + c16) * SAPC + ks4 * 32 + q * 8];
#pragma unroll
            for (int ra = 0; ra < 4; ++ra)
#pragma unroll
                for (int ct = 0; ct < 4; ++ct)
                    acc[ra][ct] = __builtin_amdgcn_mfma_f32_16x16x32_bf16(af[ra], bcur[ct], acc[ra][ct], 0, 0, 0);
#pragma unroll
            for (int ct = 0; ct < 4; ++ct) bcur[ct] = bnxt[ct];
        }
    }

    // epilogue: tanh + dot with w, reduce over the 128 cols
    float bc[4], wc[4];
#pragma unroll
    for (int ct = 0; ct < 4; ++ct) {
        const int col = wcolg * 64 + ct * 16 + c16;
        bc[ct] = bias[pair * OUTD + col];
        wc[ct] = wvec[col];
    }
#pragma unroll
    for (int ra = 0; ra < 4; ++ra) {
#pragma unroll
        for (int reg = 0; reg < 4; ++reg) {
            float s = 0.f;
#pragma unroll
            for (int ct = 0; ct < 4; ++ct)
                s += fast_tanh(acc[ra][ct][reg] + bc[ct]) * wc[ct];
            // reduce across the 16 lanes of this quad (they hold the 16 cols)
#pragma unroll
            for (int off = 1; off < 16; off <<= 1) s += __shfl_xor(s, off, 64);
            if (c16 == 0)
                sred[wrow * 64 + ra * 16 + q * 4 + reg][wcolg] = s;
        }
    }
    __syncthreads();
    if (t < 128)
        att[(size_t)pair * L + rowbase + t] = sred[t][0] + sred[t][1];
}

// ---------------------------------------------------------------------------
// K5: masked softmax over L + weighted sum. 1024 threads: 4-way L split.
// ---------------------------------------------------------------------------
template <int L>
__global__ __launch_bounds__(1024) void k_soft(
    const float* __restrict__ seq, const int* __restrict__ mask,
    const float* __restrict__ att, float* __restrict__ outp)
{
    const int pair = blockIdx.x;
    const int t = threadIdx.x;
    __shared__ float p[L];
    __shared__ float red[8];
    __shared__ float red2[4][DIM];

    float lmax = -INFINITY;
    if (t < 256) {
#pragma unroll
        for (int k = 0; k < L / 256; ++k) {
            const int i = t + k * 256;
            float a = att[(size_t)pair * L + i];
            a = mask[pair * L + i] ? a : NEGV;
            p[i] = a;
            lmax = fmaxf(lmax, a);
        }
#pragma unroll
        for (int off = 32; off > 0; off >>= 1) lmax = fmaxf(lmax, __shfl_xor(lmax, off, 64));
        if ((t & 63) == 0) red[t >> 6] = lmax;
    }
    __syncthreads();
    if (t < 256) {
        const float gmax = fmaxf(fmaxf(red[0], red[1]), fmaxf(red[2], red[3]));
        float lsum = 0.f;
#pragma unroll
        for (int k = 0; k < L / 256; ++k) {
            const int i = t + k * 256;
            const float e = expf(p[i] - gmax);
            p[i] = e;
            lsum += e;
        }
#pragma unroll
        for (int off = 32; off > 0; off >>= 1) lsum += __shfl_xor(lsum, off, 64);
        if ((t & 63) == 0) red[4 + (t >> 6)] = lsum;
    }
    __syncthreads();

    // weighted sum: thread (lg, d) accumulates its L/4 chunk
    const int d = t & 255, lg = t >> 8;
    constexpr int L4 = L / 4;
    const float* sp = seq + (size_t)pair * L * DIM + d;
    float o = 0.f;
    for (int l = lg * L4; l < (lg + 1) * L4; ++l) o += p[l] * sp[(size_t)l * DIM];
    red2[lg][d] = o;
    __syncthreads();
    if (t < 256) {
        const float inv = 1.f / (red[4] + red[5] + red[6] + red[7]);
        outp[pair * DIM + t] = (red2[0][t] + red2[1][t] + red2[2][t] + red2[3][t]) * inv;
    }
}

// ---------------------------------------------------------------------------
extern "C" void kernel_launch(void* const* d_in, const int* in_sizes, int n_in,
                              void* d_out, int out_size, void* d_ws, size_t ws_size,
                              hipStream_t stream) {
    const float* claim    = (const float*)d_in[0];
    const int*   cmask    = (const int*)  d_in[1];
    const float* evidence = (const float*)d_in[2];
    const int*   emask    = (const int*)  d_in[3];
    const float* W1       = (const float*)d_in[4];
    const float* w2       = (const float*)d_in[5];
    const float* W2       = (const float*)d_in[6];
    const float* w1       = (const float*)d_in[7];
    float* out = (float*)d_out;

    float* ws = (float*)d_ws;
    float* cmean  = ws;                        // 65536
    float* emean  = cmean + BE * DIM;          // 65536
    float* bias_e = emean + BE * DIM;          // 32768
    float* bias_c = bias_e + BE * OUTD;        // 32768
    float* att_e  = bias_c + BE * OUTD;        // 131072
    float* att_c  = att_e + BE * LEV;          // 65536
    unsigned short* WT1 = (unsigned short*)(att_c + BE * LCL);
    unsigned short* WT2 = WT1 + OUTD * DIM;

    k_zero<<<512, 256, 0, stream>>>(cmean);    // zeros cmean+emean (contiguous)
    k_prepW<<<dim3(128, 2), 256, 0, stream>>>(W1, W2, WT1, WT2);
    k_pmean<<<dim3(BE, 24), 256, 0, stream>>>(claim, evidence, cmean, emean);
    k_biasgemm<<<BE, 256, 0, stream>>>(cmean, emean, W1, W2, bias_e, bias_c);
    k_att<LEV><<<dim3(BE, 4), 256, 0, stream>>>(evidence, WT1, w2, bias_e, att_e);
    k_att<LCL><<<dim3(BE, 2), 256, 0, stream>>>(claim, WT2, w1, bias_c, att_c);
    // output order: c_hat first, then e_hat
    k_soft<LEV><<<BE, 1024, 0, stream>>>(evidence, emask, att_e, out + BE * DIM);
    k_soft<LCL><<<BE, 1024, 0, stream>>>(claim, cmask, att_c, out);
}

// Round 3
// 344.858 us; speedup vs baseline: 1.5694x; 1.0412x over previous
//
#include <hip/hip_runtime.h>
#include <hip/hip_bf16.h>
#include <math.h>

#define BE   256
#define DIM  256
#define OUTD 128
#define LCL  256
#define LEV  512
#define NEGV -1e18f

typedef short  bf16x8  __attribute__((ext_vector_type(8)));
typedef float  floatx4 __attribute__((ext_vector_type(4)));

union BF1 { __hip_bfloat16 h; unsigned short u; };
union BF2 { __hip_bfloat162 h; unsigned int u; };

__device__ __forceinline__ float fast_tanh(float x) {
    float xc = fminf(fmaxf(x, -15.f), 15.f);
    float e = __expf(2.f * xc);                       // e^{2x}
    return (e - 1.f) * __builtin_amdgcn_rcpf(e + 1.f);
}

// ---------------------------------------------------------------------------
// K1: stage-A mean partials (no atomics) + W-transpose fold.
// blocks [0,3072): pair=b/12, chunk=b%12; chunk<4 -> claim 64-row chunk,
// else evidence 64-row chunk. Writes partial[b][256].
// blocks [3072,3328): convert+transpose W[:D] -> bf16 W^T.
// ---------------------------------------------------------------------------
__global__ __launch_bounds__(256) void k_meanprep(
    const float* __restrict__ claim, const float* __restrict__ evidence,
    const float* __restrict__ W1, const float* __restrict__ W2,
    float* __restrict__ partial,
    unsigned short* __restrict__ WT1, unsigned short* __restrict__ WT2)
{
    const int b = blockIdx.x;
    const int t = threadIdx.x;
    if (b >= 3072) {
        const int idx = b - 3072;          // 0..255
        const int side = idx >> 7;
        const int n = idx & 127;
        const float* W = side ? W2 : W1;
        unsigned short* WT = side ? WT2 : WT1;
        BF1 c; c.h = __float2bfloat16(W[(size_t)t * OUTD + n]);
        WT[n * DIM + t] = c.u;
        return;
    }
    const int pair = b / 12;
    const int chunk = b % 12;
    const float* src = (chunk < 4)
        ? claim + ((size_t)pair * LCL + chunk * 64) * DIM
        : evidence + ((size_t)pair * LEV + (chunk - 4) * 64) * DIM;
    float s = 0.f;
#pragma unroll
    for (int r = 0; r < 64; ++r) s += src[r * DIM + t];
    partial[(size_t)b * DIM + t] = s;
}

// ---------------------------------------------------------------------------
// K2: reduce partials -> means, then bias GEMMs. 512 threads:
// side = t>>8 (0: claim-mean @ W1[D:] -> bias_e, 1: evid-mean @ W2[D:] -> bias_c)
// o = t&127, dh = (t>>7)&1 splits the D-loop in half; LDS combine.
// ---------------------------------------------------------------------------
__global__ __launch_bounds__(512) void k_redbias(
    const float* __restrict__ partial,
    const float* __restrict__ W1, const float* __restrict__ W2,
    float* __restrict__ bias_e, float* __restrict__ bias_c)
{
    const int pair = blockIdx.x;
    const int t = threadIdx.x;
    __shared__ float sm[2][DIM];
    __shared__ float sb[2][2][OUTD];
    if (t < 256) {
        float s = 0.f;
#pragma unroll
        for (int j = 0; j < 4; ++j) s += partial[((size_t)pair * 12 + j) * DIM + t];
        sm[0][t] = s * (1.f / LCL);
    } else {
        const int t2 = t - 256;
        float s = 0.f;
#pragma unroll
        for (int j = 4; j < 12; ++j) s += partial[((size_t)pair * 12 + j) * DIM + t2];
        sm[1][t2] = s * (1.f / LEV);
    }
    __syncthreads();
    const int side = t >> 8, o = t & 127, dh = (t >> 7) & 1;
    const float* W = side ? W2 : W1;
    const float* m = sm[side];
    float s = 0.f;
#pragma unroll 8
    for (int i = 0; i < 128; ++i) {
        const int d = dh * 128 + i;
        s += m[d] * W[(size_t)(DIM + d) * OUTD + o];
    }
    sb[side][dh][o] = s;
    __syncthreads();
    if (t < 256) {
        const int sd = t >> 7, oo = t & 127;
        const float bv = sb[sd][0][oo] + sb[sd][1][oo];
        (sd ? bias_c : bias_e)[pair * OUTD + oo] = bv;
    }
}

// ---------------------------------------------------------------------------
// K3: MFMA attention-score kernel (unchanged structure from R1).
// att[l] = sum_o tanh( (seq @ W[:D])[l,o] + bias[o] ) * w[o]
// ---------------------------------------------------------------------------
template <int L>
__global__ __launch_bounds__(256) void k_att(
    const float* __restrict__ seq, const unsigned short* __restrict__ WT,
    const float* __restrict__ wvec, const float* __restrict__ bias,
    float* __restrict__ att)
{
    constexpr int SAPC = 136;                 // padded k-stride (128+8) in bf16
    __shared__ unsigned short sA[128 * SAPC]; // 34816 B
    __shared__ float sred[128][2];

    const int pair = blockIdx.x;
    const int rowbase = blockIdx.y * 128;
    const int t = threadIdx.x;
    const int lane = t & 63;
    const int wv = t >> 6;
    const int wrow = wv >> 1, wcolg = wv & 1;
    const int q = lane >> 4, c16 = lane & 15;

    const float4* sp4 = (const float4*)(seq + ((size_t)pair * L + rowbase) * DIM);

    floatx4 acc[4][4];
#pragma unroll
    for (int ra = 0; ra < 4; ++ra)
#pragma unroll
        for (int ct = 0; ct < 4; ++ct) acc[ra][ct] = (floatx4){0.f, 0.f, 0.f, 0.f};

    const unsigned short* wbase = WT + (size_t)(wcolg * 64 + c16) * DIM + q * 8;
    bf16x8 bcur[4], bnxt[4];
#pragma unroll
    for (int ct = 0; ct < 4; ++ct)
        bcur[ct] = *(const bf16x8*)(wbase + ct * 16 * DIM);

    for (int kc = 0; kc < 2; ++kc) {
        __syncthreads();
#pragma unroll
        for (int i = 0; i < 16; ++i) {
            const int idx = t + i * 256;
            const int row = idx >> 5;
            const int f4 = idx & 31;
            const float4 v = sp4[row * 64 + kc * 32 + f4];
            BF2 lo, hi;
            lo.h = __float22bfloat162_rn(make_float2(v.x, v.y));
            hi.h = __float22bfloat162_rn(make_float2(v.z, v.w));
            *(uint2*)&sA[row * SAPC + f4 * 4] = make_uint2(lo.u, hi.u);
        }
        __syncthreads();
#pragma unroll
        for (int ks4 = 0; ks4 < 4; ++ks4) {
            const int ks = kc * 4 + ks4;
            if (ks < 7) {
#pragma unroll
                for (int ct = 0; ct < 4; ++ct)
                    bnxt[ct] = *(const bf16x8*)(wbase + ct * 16 * DIM + (ks + 1) * 32);
            }
            bf16x8 af[4];
#pragma unroll
            for (int ra = 0; ra < 4; ++ra)
                af[ra] = *(const bf16x8*)&sA[(wrow * 64 + ra * 16 + c16) * SAPC + ks4 * 32 + q * 8];
#pragma unroll
            for (int ra = 0; ra < 4; ++ra)
#pragma unroll
                for (int ct = 0; ct < 4; ++ct)
                    acc[ra][ct] = __builtin_amdgcn_mfma_f32_16x16x32_bf16(af[ra], bcur[ct], acc[ra][ct], 0, 0, 0);
#pragma unroll
            for (int ct = 0; ct < 4; ++ct) bcur[ct] = bnxt[ct];
        }
    }

    float bc[4], wc[4];
#pragma unroll
    for (int ct = 0; ct < 4; ++ct) {
        const int col = wcolg * 64 + ct * 16 + c16;
        bc[ct] = bias[pair * OUTD + col];
        wc[ct] = wvec[col];
    }
#pragma unroll
    for (int ra = 0; ra < 4; ++ra) {
#pragma unroll
        for (int reg = 0; reg < 4; ++reg) {
            float s = 0.f;
#pragma unroll
            for (int ct = 0; ct < 4; ++ct)
                s += fast_tanh(acc[ra][ct][reg] + bc[ct]) * wc[ct];
#pragma unroll
            for (int off = 1; off < 16; off <<= 1) s += __shfl_xor(s, off, 64);
            if (c16 == 0)
                sred[wrow * 64 + ra * 16 + q * 4 + reg][wcolg] = s;
        }
    }
    __syncthreads();
    if (t < 128)
        att[(size_t)pair * L + rowbase + t] = sred[t][0] + sred[t][1];
}

// ---------------------------------------------------------------------------
// K4: masked softmax + weighted sum. 1024 thr: softmax by waves 0-3,
// wsum by all 16 waves: lg = t>>6 picks an L/16 chunk, d4 = t&63 a float4.
// ---------------------------------------------------------------------------
template <int L>
__global__ __launch_bounds__(1024) void k_soft(
    const float* __restrict__ seq, const int* __restrict__ mask,
    const float* __restrict__ att, float* __restrict__ outp)
{
    const int pair = blockIdx.x;
    const int t = threadIdx.x;
    __shared__ float p[L];
    __shared__ float red[8];
    __shared__ float4 red2[16][64];

    float lmax = -INFINITY;
    if (t < 256) {
#pragma unroll
        for (int k = 0; k < L / 256; ++k) {
            const int i = t + k * 256;
            float a = att[(size_t)pair * L + i];
            a = mask[pair * L + i] ? a : NEGV;
            p[i] = a;
            lmax = fmaxf(lmax, a);
        }
#pragma unroll
        for (int off = 32; off > 0; off >>= 1) lmax = fmaxf(lmax, __shfl_xor(lmax, off, 64));
        if ((t & 63) == 0) red[t >> 6] = lmax;
    }
    __syncthreads();
    if (t < 256) {
        const float gmax = fmaxf(fmaxf(red[0], red[1]), fmaxf(red[2], red[3]));
        float lsum = 0.f;
#pragma unroll
        for (int k = 0; k < L / 256; ++k) {
            const int i = t + k * 256;
            const float e = expf(p[i] - gmax);
            p[i] = e;
            lsum += e;
        }
#pragma unroll
        for (int off = 32; off > 0; off >>= 1) lsum += __shfl_xor(lsum, off, 64);
        if ((t & 63) == 0) red[4 + (t >> 6)] = lsum;
    }
    __syncthreads();

    const int d4 = t & 63, lg = t >> 6;
    constexpr int LC = L / 16;
    const float4* sp4 = (const float4*)(seq + (size_t)pair * L * DIM);
    float4 o = make_float4(0.f, 0.f, 0.f, 0.f);
    for (int l = lg * LC; l < (lg + 1) * LC; ++l) {
        const float pl = p[l];
        const float4 v = sp4[l * 64 + d4];
        o.x += pl * v.x; o.y += pl * v.y; o.z += pl * v.z; o.w += pl * v.w;
    }
    red2[lg][d4] = o;
    __syncthreads();
    if (t < 64) {
        float4 s = make_float4(0.f, 0.f, 0.f, 0.f);
#pragma unroll
        for (int j = 0; j < 16; ++j) {
            const float4 v = red2[j][t];
            s.x += v.x; s.y += v.y; s.z += v.z; s.w += v.w;
        }
        const float inv = 1.f / (red[4] + red[5] + red[6] + red[7]);
        ((float4*)(outp + (size_t)pair * DIM))[t] =
            make_float4(s.x * inv, s.y * inv, s.z * inv, s.w * inv);
    }
}

// ---------------------------------------------------------------------------
extern "C" void kernel_launch(void* const* d_in, const int* in_sizes, int n_in,
                              void* d_out, int out_size, void* d_ws, size_t ws_size,
                              hipStream_t stream) {
    const float* claim    = (const float*)d_in[0];
    const int*   cmask    = (const int*)  d_in[1];
    const float* evidence = (const float*)d_in[2];
    const int*   emask    = (const int*)  d_in[3];
    const float* W1       = (const float*)d_in[4];
    const float* w2       = (const float*)d_in[5];
    const float* W2       = (const float*)d_in[6];
    const float* w1       = (const float*)d_in[7];
    float* out = (float*)d_out;

    float* ws = (float*)d_ws;
    float* partial = ws;                         // 3072*256 = 786432
    float* bias_e  = partial + 3072 * DIM;       // 32768
    float* bias_c  = bias_e + BE * OUTD;         // 32768
    float* att_e   = bias_c + BE * OUTD;         // 131072
    float* att_c   = att_e + BE * LEV;           // 65536
    unsigned short* WT1 = (unsigned short*)(att_c + BE * LCL);
    unsigned short* WT2 = WT1 + OUTD * DIM;

    k_meanprep<<<3328, 256, 0, stream>>>(claim, evidence, W1, W2, partial, WT1, WT2);
    k_redbias<<<BE, 512, 0, stream>>>(partial, W1, W2, bias_e, bias_c);
    k_att<LEV><<<dim3(BE, 4), 256, 0, stream>>>(evidence, WT1, w2, bias_e, att_e);
    k_att<LCL><<<dim3(BE, 2), 256, 0, stream>>>(claim, WT2, w1, bias_c, att_c);
    // output order: c_hat first, then e_hat
    k_soft<LEV><<<BE, 1024, 0, stream>>>(evidence, emask, att_e, out + BE * DIM);
    k_soft<LCL><<<BE, 1024, 0, stream>>>(claim, cmask, att_c, out);
}